// Round 1
// baseline (23016.165 us; speedup 1.0000x reference)
//
#include <hip/hip_runtime.h>

#define NN 100000
#define HD 128
#define EE 1600000

// ---------------------------------------------------------------- counts
__global__ __launch_bounds__(256) void count_kernel(
    const int* __restrict__ ei_pp, const int* __restrict__ ei_dd,
    const int* __restrict__ ei_p2d,
    float* __restrict__ cnt_pp, float* __restrict__ cnt_dd,
    float* __restrict__ cnt_p2d, float* __restrict__ cnt_d2p, int E)
{
    int gid = blockIdx.x * 256 + threadIdx.x;
    if (gid < E) {
        unsafeAtomicAdd(cnt_pp + ei_pp[E + gid], 1.0f);          // pp dst = row1
    } else if (gid < 2 * E) {
        int e = gid - E;
        unsafeAtomicAdd(cnt_dd + ei_dd[E + e], 1.0f);            // dd dst = row1
    } else if (gid < 3 * E) {
        int e = gid - 2 * E;
        unsafeAtomicAdd(cnt_p2d + ei_p2d[E + e], 1.0f);          // p2d dst = row1 (dual)
        unsafeAtomicAdd(cnt_d2p + ei_p2d[e],     1.0f);          // d2p dst = row0 (primal)
    }
}

__global__ __launch_bounds__(256) void recip_kernel(float* __restrict__ c, int n)
{
    int i = blockIdx.x * 256 + threadIdx.x;
    if (i < n) c[i] = 1.0f / fmaxf(c[i], 1.0f);
}

// ------------------------------------------------- fused-weight prep
// Wt layout per cfg: [k=384][j=128], cfg: 0=l0 primal, 1=l0 dual, 2=l1 primal, 3=l1 dual
__global__ __launch_bounds__(256) void prep_w_kernel(
    const float* __restrict__ ll, const float* __restrict__ lr, float* __restrict__ Wt)
{
    int gid = blockIdx.x * 256 + threadIdx.x;
    if (gid >= 4 * 384 * 128) return;
    int cfg = gid / (384 * 128);
    int rem = gid - cfg * (384 * 128);
    int k = rem >> 7;
    int j = rem & 127;
    int l  = cfg >> 1;
    int ia = (cfg & 1) ? 1 : 0;   // agg1 weight index (pp / dd)
    int ib = (cfg & 1) ? 2 : 3;   // agg2 weight index (p2d / d2p)
    float v;
    if (k < 128)
        v = ll[((l * 4 + ia) * 128 + j) * 128 + k];
    else if (k < 256)
        v = ll[((l * 4 + ib) * 128 + j) * 128 + (k - 128)];
    else
        v = lr[((l * 4 + ia) * 128 + j) * 128 + (k - 256)]
          + lr[((l * 4 + ib) * 128 + j) * 128 + (k - 256)];
    Wt[gid] = v;
}

// ---------------------------------------------------------------- encoder
template <int IN>
__global__ __launch_bounds__(128) void encoder_kernel(
    const float* __restrict__ x, const float* __restrict__ w,
    const float* __restrict__ b, float* __restrict__ h, int n)
{
    int node = blockIdx.x;
    int j = threadIdx.x;
    __shared__ float xs[IN];
    if (j < IN) xs[j] = x[node * IN + j];
    __syncthreads();
    float acc = b[j];
#pragma unroll
    for (int k = 0; k < IN; ++k) acc += xs[k] * w[j * IN + k];
    h[(size_t)node * HD + j] = fmaxf(acc, 0.0f);
}

// ---------------------------------------------------------------- scatter (atomic segment-sum)
__global__ __launch_bounds__(256) void scatter_kernel(
    const float* __restrict__ src, const int* __restrict__ sidx,
    const int* __restrict__ didx, float* __restrict__ agg, int E)
{
    int gid = blockIdx.x * 256 + threadIdx.x;
    int e = gid >> 5;
    if (e >= E) return;
    int c = (gid & 31) << 2;
    int s = sidx[e], d = didx[e];
    const float4 v = *reinterpret_cast<const float4*>(src + (size_t)s * HD + c);
    float* dst = agg + (size_t)d * HD + c;
    unsafeAtomicAdd(dst + 0, v.x);
    unsafeAtomicAdd(dst + 1, v.y);
    unsafeAtomicAdd(dst + 2, v.z);
    unsafeAtomicAdd(dst + 3, v.w);
}

// ---------------------------------------------------------------- fused SAGE GEMM
// out[i][j] = relu(b1[j]+b2[j] + sum_k X[i][k]*Wt[k][j]),
// X = [agg1*inv1 | agg2*inv2 | h], K=384. 32 nodes per block, 256 threads.
__global__ __launch_bounds__(256) void sage_gemm(
    const float* agg1, const float* __restrict__ inv1,
    const float* __restrict__ agg2, const float* __restrict__ inv2,
    const float* __restrict__ hsrc, const float* __restrict__ Wt,
    const float* __restrict__ b1, const float* __restrict__ b2,
    float* out, int n, int doRelu)
{
    __shared__ __align__(16) float Ws[32][128];
    __shared__ __align__(16) float Xs[32][36];
    const int tid = threadIdx.x;
    const int tj = tid & 31;   // col group: cols tj*4..tj*4+3
    const int ti = tid >> 5;   // node group: nodes ti*4..ti*4+3
    const int nodeBase = blockIdx.x * 32;
    float acc[4][4] = {};

    for (int k0 = 0; k0 < 384; k0 += 32) {
        const float* src; const float* invp;
        if (k0 < 128)       { src = agg1; invp = inv1; }
        else if (k0 < 256)  { src = agg2; invp = inv2; }
        else                { src = hsrc; invp = nullptr; }
        const int ksub = k0 & 127;
        // stage W chunk: 32x128
#pragma unroll
        for (int it = 0; it < 16; ++it) {
            int idx = it * 256 + tid;
            Ws[idx >> 7][idx & 127] = Wt[(k0 + (idx >> 7)) * 128 + (idx & 127)];
        }
        // stage X chunk transposed: Xs[kk][i]
#pragma unroll
        for (int it = 0; it < 4; ++it) {
            int idx = it * 256 + tid;
            int i = idx >> 5, kk = idx & 31;
            int node = nodeBase + i;
            float v = 0.0f;
            if (node < n) {
                v = src[(size_t)node * HD + ksub + kk];
                if (invp) v *= invp[node];
            }
            Xs[kk][i] = v;
        }
        __syncthreads();
#pragma unroll
        for (int kk = 0; kk < 32; ++kk) {
            const float4 xv = *reinterpret_cast<const float4*>(&Xs[kk][ti * 4]);
            const float4 wv = *reinterpret_cast<const float4*>(&Ws[kk][tj * 4]);
            acc[0][0] += xv.x * wv.x; acc[0][1] += xv.x * wv.y; acc[0][2] += xv.x * wv.z; acc[0][3] += xv.x * wv.w;
            acc[1][0] += xv.y * wv.x; acc[1][1] += xv.y * wv.y; acc[1][2] += xv.y * wv.z; acc[1][3] += xv.y * wv.w;
            acc[2][0] += xv.z * wv.x; acc[2][1] += xv.z * wv.y; acc[2][2] += xv.z * wv.z; acc[2][3] += xv.z * wv.w;
            acc[3][0] += xv.w * wv.x; acc[3][1] += xv.w * wv.y; acc[3][2] += xv.w * wv.z; acc[3][3] += xv.w * wv.w;
        }
        __syncthreads();
    }

    float4 bias;
    bias.x = b1[tj * 4 + 0] + b2[tj * 4 + 0];
    bias.y = b1[tj * 4 + 1] + b2[tj * 4 + 1];
    bias.z = b1[tj * 4 + 2] + b2[tj * 4 + 2];
    bias.w = b1[tj * 4 + 3] + b2[tj * 4 + 3];
#pragma unroll
    for (int a = 0; a < 4; ++a) {
        int node = nodeBase + ti * 4 + a;
        if (node < n) {
            float4 r;
            r.x = acc[a][0] + bias.x;
            r.y = acc[a][1] + bias.y;
            r.z = acc[a][2] + bias.z;
            r.w = acc[a][3] + bias.w;
            if (doRelu) {
                r.x = fmaxf(r.x, 0.0f); r.y = fmaxf(r.y, 0.0f);
                r.z = fmaxf(r.z, 0.0f); r.w = fmaxf(r.w, 0.0f);
            }
            *reinterpret_cast<float4*>(out + (size_t)node * HD + tj * 4) = r;
        }
    }
}

// ---------------------------------------------------------------- decoder (OUT=3)
__global__ __launch_bounds__(128) void decoder_kernel(
    const float* __restrict__ hp, const float* __restrict__ hd,
    const float* __restrict__ wp, const float* __restrict__ bp,
    const float* __restrict__ wd, const float* __restrict__ bd,
    float* __restrict__ out, int n)
{
    int b = blockIdx.x;
    const float* h; const float* w; const float* bb; float* o;
    if (b < n) { h = hp + (size_t)b * HD; w = wp; bb = bp; o = out + (size_t)b * 3; }
    else { int nd = b - n; h = hd + (size_t)nd * HD; w = wd; bb = bd; o = out + (size_t)n * 3 + (size_t)nd * 3; }
    int t = threadIdx.x;
    float x = h[t];
    float p0 = x * w[0 * HD + t];
    float p1 = x * w[1 * HD + t];
    float p2 = x * w[2 * HD + t];
#pragma unroll
    for (int off = 32; off > 0; off >>= 1) {
        p0 += __shfl_down(p0, off, 64);
        p1 += __shfl_down(p1, off, 64);
        p2 += __shfl_down(p2, off, 64);
    }
    __shared__ float red[2][3];
    if ((t & 63) == 0) { int wv = t >> 6; red[wv][0] = p0; red[wv][1] = p1; red[wv][2] = p2; }
    __syncthreads();
    if (t < 3) o[t] = red[0][t] + red[1][t] + bb[t];
}

// ---------------------------------------------------------------- launch
extern "C" void kernel_launch(void* const* d_in, const int* in_sizes, int n_in,
                              void* d_out, int out_size, void* d_ws, size_t ws_size,
                              hipStream_t stream)
{
    const float* x_p     = (const float*)d_in[0];
    const float* x_d     = (const float*)d_in[1];
    const int*   ei_pp   = (const int*)d_in[2];
    const int*   ei_dd   = (const int*)d_in[3];
    const int*   ei_p2d  = (const int*)d_in[4];
    const float* enc_p_w = (const float*)d_in[5];
    const float* enc_p_b = (const float*)d_in[6];
    const float* enc_d_w = (const float*)d_in[7];
    const float* enc_d_b = (const float*)d_in[8];
    const float* lin_l_w = (const float*)d_in[9];
    const float* lin_l_b = (const float*)d_in[10];
    const float* lin_r_w = (const float*)d_in[11];
    const float* dec_p_w = (const float*)d_in[12];
    const float* dec_p_b = (const float*)d_in[13];
    const float* dec_d_w = (const float*)d_in[14];
    const float* dec_d_b = (const float*)d_in[15];
    float* out = (float*)d_out;

    const int N = NN, E = EE;
    const size_t NHs = (size_t)N * HD;
    float* ws  = (float*)d_ws;
    float* A    = ws;
    float* B    = A + NHs;
    float* C    = B + NHs;
    float* D    = C + NHs;
    float* Ebuf = D + NHs;
    float* cnt  = Ebuf + NHs;            // 4*N
    float* cnt_pp  = cnt;
    float* cnt_dd  = cnt + N;
    float* cnt_p2d = cnt + 2 * N;
    float* cnt_d2p = cnt + 3 * N;
    float* Wt = cnt + 4 * (size_t)N;     // 4 * 384*128

    #define BL(b_l, b_i) (lin_l_b + ((b_l) * 4 + (b_i)) * HD)

    // degree counts (shared by both layers) + fused weights
    hipMemsetAsync(cnt, 0, 4 * N * sizeof(float), stream);
    count_kernel<<<(3 * E + 255) / 256, 256, 0, stream>>>(
        ei_pp, ei_dd, ei_p2d, cnt_pp, cnt_dd, cnt_p2d, cnt_d2p, E);
    recip_kernel<<<(4 * N + 255) / 256, 256, 0, stream>>>(cnt, 4 * N);
    prep_w_kernel<<<(4 * 384 * 128 + 255) / 256, 256, 0, stream>>>(lin_l_w, lin_r_w, Wt);

    // encoders
    encoder_kernel<16><<<N, 128, 0, stream>>>(x_p, enc_p_w, enc_p_b, A, N);
    encoder_kernel<8><<<N, 128, 0, stream>>>(x_d, enc_d_w, enc_d_b, B, N);

    const int SCAT_B = (E * 32 + 255) / 256;
    const int GEMM_B = (N + 31) / 32;

    // ---------------- layer 0 : hp=A, hd=B ----------------
    hipMemsetAsync(C, 0, NHs * sizeof(float), stream);
    scatter_kernel<<<SCAT_B, 256, 0, stream>>>(A, ei_pp,      ei_pp + E,  C, E);  // pp  -> primal
    hipMemsetAsync(D, 0, NHs * sizeof(float), stream);
    scatter_kernel<<<SCAT_B, 256, 0, stream>>>(B, ei_p2d + E, ei_p2d,     D, E);  // d2p -> primal
    sage_gemm<<<GEMM_B, 256, 0, stream>>>(C, cnt_pp, D, cnt_d2p, A,
        Wt + 0 * 384 * 128, BL(0, 0), BL(0, 3), C, N, 1);                          // new hp -> C
    hipMemsetAsync(D, 0, NHs * sizeof(float), stream);
    scatter_kernel<<<SCAT_B, 256, 0, stream>>>(B, ei_dd,      ei_dd + E,  D, E);  // dd  -> dual
    hipMemsetAsync(Ebuf, 0, NHs * sizeof(float), stream);
    scatter_kernel<<<SCAT_B, 256, 0, stream>>>(A, ei_p2d,     ei_p2d + E, Ebuf, E); // p2d -> dual
    sage_gemm<<<GEMM_B, 256, 0, stream>>>(D, cnt_dd, Ebuf, cnt_p2d, B,
        Wt + 1 * 384 * 128, BL(0, 1), BL(0, 2), D, N, 1);                          // new hd -> D

    // ---------------- layer 1 : hp=C, hd=D ----------------
    hipMemsetAsync(A, 0, NHs * sizeof(float), stream);
    scatter_kernel<<<SCAT_B, 256, 0, stream>>>(C, ei_pp,      ei_pp + E,  A, E);
    hipMemsetAsync(B, 0, NHs * sizeof(float), stream);
    scatter_kernel<<<SCAT_B, 256, 0, stream>>>(D, ei_p2d + E, ei_p2d,     B, E);
    sage_gemm<<<GEMM_B, 256, 0, stream>>>(A, cnt_pp, B, cnt_d2p, C,
        Wt + 2 * 384 * 128, BL(1, 0), BL(1, 3), A, N, 1);                          // new hp -> A
    hipMemsetAsync(B, 0, NHs * sizeof(float), stream);
    scatter_kernel<<<SCAT_B, 256, 0, stream>>>(D, ei_dd,      ei_dd + E,  B, E);
    hipMemsetAsync(Ebuf, 0, NHs * sizeof(float), stream);
    scatter_kernel<<<SCAT_B, 256, 0, stream>>>(C, ei_p2d,     ei_p2d + E, Ebuf, E);
    sage_gemm<<<GEMM_B, 256, 0, stream>>>(B, cnt_dd, Ebuf, cnt_p2d, D,
        Wt + 3 * 384 * 128, BL(1, 1), BL(1, 2), B, N, 1);                          // new hd -> B

    // decoders: primal from A, dual from B
    decoder_kernel<<<2 * N, 128, 0, stream>>>(A, B, dec_p_w, dec_p_b, dec_d_w, dec_d_b, out, N);

    #undef BL
}

// Round 4
// 3441.719 us; speedup vs baseline: 6.6874x; 6.6874x over previous
//
#include <hip/hip_runtime.h>

#define NN 100000
#define HD 128
#define EE 1600000

// ---------------------------------------------------------------- degree count (int atomics)
// deg layout: [pp | dd | p2d | d2p], each N ints
__global__ __launch_bounds__(256) void deg_kernel(
    const int* __restrict__ ei_pp, const int* __restrict__ ei_dd,
    const int* __restrict__ ei_p2d, int* __restrict__ deg, int E, int N)
{
    int gid = blockIdx.x * 256 + threadIdx.x;
    if (gid < E) {
        atomicAdd(deg + ei_pp[E + gid], 1);
    } else if (gid < 2 * E) {
        int e = gid - E;
        atomicAdd(deg + N + ei_dd[E + e], 1);
    } else if (gid < 3 * E) {
        int e = gid - 2 * E;
        atomicAdd(deg + 2 * N + ei_p2d[E + e], 1);   // p2d: dst = dual (row1)
        atomicAdd(deg + 3 * N + ei_p2d[e], 1);       // d2p: dst = primal (row0)
    }
}

// ---------------------------------------------------------------- 4-way parallel exclusive scan
// one block per CSR; emits rowptr and cursor (= rowptr working copy)
__global__ __launch_bounds__(1024) void scan_kernel(
    const int* __restrict__ deg, int* __restrict__ rowptr,
    int* __restrict__ cursor, int n)
{
    int t = blockIdx.x;
    const int* d = deg + (size_t)t * n;
    int* rp = rowptr + (size_t)t * (n + 1);
    int* cu = cursor + (size_t)t * n;
    __shared__ int sdata[1024];
    __shared__ int sbase;
    if (threadIdx.x == 0) sbase = 0;
    __syncthreads();
    for (int chunk = 0; chunk < n; chunk += 1024) {
        int i = chunk + threadIdx.x;
        int v = (i < n) ? d[i] : 0;
        sdata[threadIdx.x] = v;
        __syncthreads();
        for (int off = 1; off < 1024; off <<= 1) {
            int x = (threadIdx.x >= off) ? sdata[threadIdx.x - off] : 0;
            __syncthreads();
            sdata[threadIdx.x] += x;
            __syncthreads();
        }
        int incl = sdata[threadIdx.x];
        int base = sbase;
        if (i < n) {
            int excl = base + incl - v;
            rp[i] = excl;
            cu[i] = excl;
        }
        __syncthreads();
        if (threadIdx.x == 1023) sbase = base + incl;
        __syncthreads();
    }
    if (threadIdx.x == 0) rp[n] = sbase;
}

// ---------------------------------------------------------------- CSR bucket fill
// esrc layout: [pp | dd | p2d | d2p], each E ints
__global__ __launch_bounds__(256) void fill_kernel(
    const int* __restrict__ ei_pp, const int* __restrict__ ei_dd,
    const int* __restrict__ ei_p2d,
    int* __restrict__ cursor, int* __restrict__ esrc, int E, int N)
{
    int gid = blockIdx.x * 256 + threadIdx.x;
    if (gid < E) {
        int s = ei_pp[gid], dd = ei_pp[E + gid];
        int pos = atomicAdd(cursor + dd, 1);
        esrc[pos] = s;
    } else if (gid < 2 * E) {
        int e = gid - E;
        int s = ei_dd[e], dd = ei_dd[E + e];
        int pos = atomicAdd(cursor + N + dd, 1);
        esrc[E + pos] = s;
    } else if (gid < 3 * E) {
        int e = gid - 2 * E;
        int sp = ei_p2d[e], sd = ei_p2d[E + e];
        int pos = atomicAdd(cursor + 2 * N + sd, 1);   // p2d: dst dual, src primal
        esrc[2 * E + pos] = sp;
        pos = atomicAdd(cursor + 3 * N + sp, 1);       // d2p: dst primal, src dual
        esrc[3 * E + pos] = sd;
    }
}

// ---------------------------------------------------------------- gather aggregation (mean fused)
// one wave per destination node; lane owns 2 columns (float2).
// src and out must NOT alias (gather reads arbitrary rows).
__global__ __launch_bounds__(256) void aggregate_kernel(
    const float* __restrict__ src, const int* __restrict__ rowptr,
    const int* __restrict__ esrc, float* __restrict__ out, int n)
{
    int node = (blockIdx.x * 256 + threadIdx.x) >> 6;
    if (node >= n) return;
    int lane = threadIdx.x & 63;
    const size_t coff = (size_t)(lane << 1);
    int e = rowptr[node], end = rowptr[node + 1];
    float iv = 1.0f / fmaxf((float)(end - e), 1.0f);
    float2 acc0 = {0.f, 0.f}, acc1 = {0.f, 0.f};
    for (; e + 1 < end; e += 2) {
        int s0 = esrc[e], s1 = esrc[e + 1];
        const float2 v0 = *reinterpret_cast<const float2*>(src + (size_t)s0 * HD + coff);
        const float2 v1 = *reinterpret_cast<const float2*>(src + (size_t)s1 * HD + coff);
        acc0.x += v0.x; acc0.y += v0.y;
        acc1.x += v1.x; acc1.y += v1.y;
    }
    if (e < end) {
        const float2 v0 = *reinterpret_cast<const float2*>(src + (size_t)esrc[e] * HD + coff);
        acc0.x += v0.x; acc0.y += v0.y;
    }
    float2 r;
    r.x = (acc0.x + acc1.x) * iv;
    r.y = (acc0.y + acc1.y) * iv;
    *reinterpret_cast<float2*>(out + (size_t)node * HD + coff) = r;
}

// ------------------------------------------------- fused-weight prep
// Wt layout per cfg: [k=384][j=128], cfg: 0=l0 primal, 1=l0 dual, 2=l1 primal, 3=l1 dual
__global__ __launch_bounds__(256) void prep_w_kernel(
    const float* __restrict__ ll, const float* __restrict__ lr, float* __restrict__ Wt)
{
    int gid = blockIdx.x * 256 + threadIdx.x;
    if (gid >= 4 * 384 * 128) return;
    int cfg = gid / (384 * 128);
    int rem = gid - cfg * (384 * 128);
    int k = rem >> 7;
    int j = rem & 127;
    int l  = cfg >> 1;
    int ia = (cfg & 1) ? 1 : 0;   // agg1 weight index (pp / dd)
    int ib = (cfg & 1) ? 2 : 3;   // agg2 weight index (p2d / d2p)
    float v;
    if (k < 128)
        v = ll[((l * 4 + ia) * 128 + j) * 128 + k];
    else if (k < 256)
        v = ll[((l * 4 + ib) * 128 + j) * 128 + (k - 128)];
    else
        v = lr[((l * 4 + ia) * 128 + j) * 128 + (k - 256)]
          + lr[((l * 4 + ib) * 128 + j) * 128 + (k - 256)];
    Wt[gid] = v;
}

// ---------------------------------------------------------------- encoder
template <int IN>
__global__ __launch_bounds__(128) void encoder_kernel(
    const float* __restrict__ x, const float* __restrict__ w,
    const float* __restrict__ b, float* __restrict__ h, int n)
{
    int node = blockIdx.x;
    int j = threadIdx.x;
    __shared__ float xs[IN];
    if (j < IN) xs[j] = x[node * IN + j];
    __syncthreads();
    float acc = b[j];
#pragma unroll
    for (int k = 0; k < IN; ++k) acc += xs[k] * w[j * IN + k];
    h[(size_t)node * HD + j] = fmaxf(acc, 0.0f);
}

// ---------------------------------------------------------------- fused SAGE GEMM
// out[i][j] = relu(b1[j]+b2[j] + sum_k X[i][k]*Wt[k][j]), X = [agg1 | agg2 | h], K=384.
// agg1/agg2 pre-normalized. out MAY alias agg1/agg2/hsrc: each block reads only
// its own 32 rows and writes them only after the K-loop; blocks' rows disjoint.
__global__ __launch_bounds__(256) void sage_gemm(
    const float* agg1, const float* agg2,
    const float* hsrc, const float* __restrict__ Wt,
    const float* __restrict__ b1, const float* __restrict__ b2,
    float* out, int n)
{
    __shared__ __align__(16) float Ws[32][128];
    __shared__ __align__(16) float Xs[32][36];
    const int tid = threadIdx.x;
    const int tj = tid & 31;   // col group: cols tj*4..tj*4+3
    const int ti = tid >> 5;   // node group: nodes ti*4..ti*4+3
    const int nodeBase = blockIdx.x * 32;
    float acc[4][4] = {};

    for (int k0 = 0; k0 < 384; k0 += 32) {
        const float* src;
        if (k0 < 128)       src = agg1;
        else if (k0 < 256)  src = agg2;
        else                src = hsrc;
        const int ksub = k0 & 127;
#pragma unroll
        for (int it = 0; it < 16; ++it) {
            int idx = it * 256 + tid;
            Ws[idx >> 7][idx & 127] = Wt[(k0 + (idx >> 7)) * 128 + (idx & 127)];
        }
#pragma unroll
        for (int it = 0; it < 4; ++it) {
            int idx = it * 256 + tid;
            int i = idx >> 5, kk = idx & 31;
            int node = nodeBase + i;
            Xs[kk][i] = (node < n) ? src[(size_t)node * HD + ksub + kk] : 0.0f;
        }
        __syncthreads();
#pragma unroll
        for (int kk = 0; kk < 32; ++kk) {
            const float4 xv = *reinterpret_cast<const float4*>(&Xs[kk][ti * 4]);
            const float4 wv = *reinterpret_cast<const float4*>(&Ws[kk][tj * 4]);
            acc[0][0] += xv.x * wv.x; acc[0][1] += xv.x * wv.y; acc[0][2] += xv.x * wv.z; acc[0][3] += xv.x * wv.w;
            acc[1][0] += xv.y * wv.x; acc[1][1] += xv.y * wv.y; acc[1][2] += xv.y * wv.z; acc[1][3] += xv.y * wv.w;
            acc[2][0] += xv.z * wv.x; acc[2][1] += xv.z * wv.y; acc[2][2] += xv.z * wv.z; acc[2][3] += xv.z * wv.w;
            acc[3][0] += xv.w * wv.x; acc[3][1] += xv.w * wv.y; acc[3][2] += xv.w * wv.z; acc[3][3] += xv.w * wv.w;
        }
        __syncthreads();
    }

    float4 bias;
    bias.x = b1[tj * 4 + 0] + b2[tj * 4 + 0];
    bias.y = b1[tj * 4 + 1] + b2[tj * 4 + 1];
    bias.z = b1[tj * 4 + 2] + b2[tj * 4 + 2];
    bias.w = b1[tj * 4 + 3] + b2[tj * 4 + 3];
#pragma unroll
    for (int a = 0; a < 4; ++a) {
        int node = nodeBase + ti * 4 + a;
        if (node < n) {
            float4 r;
            r.x = fmaxf(acc[a][0] + bias.x, 0.0f);
            r.y = fmaxf(acc[a][1] + bias.y, 0.0f);
            r.z = fmaxf(acc[a][2] + bias.z, 0.0f);
            r.w = fmaxf(acc[a][3] + bias.w, 0.0f);
            *reinterpret_cast<float4*>(out + (size_t)node * HD + tj * 4) = r;
        }
    }
}

// ---------------------------------------------------------------- decoder (OUT=3)
__global__ __launch_bounds__(128) void decoder_kernel(
    const float* __restrict__ hp, const float* __restrict__ hd,
    const float* __restrict__ wp, const float* __restrict__ bp,
    const float* __restrict__ wd, const float* __restrict__ bd,
    float* __restrict__ out, int n)
{
    int b = blockIdx.x;
    const float* h; const float* w; const float* bb; float* o;
    if (b < n) { h = hp + (size_t)b * HD; w = wp; bb = bp; o = out + (size_t)b * 3; }
    else { int nd = b - n; h = hd + (size_t)nd * HD; w = wd; bb = bd; o = out + (size_t)n * 3 + (size_t)nd * 3; }
    int t = threadIdx.x;
    float x = h[t];
    float p0 = x * w[0 * HD + t];
    float p1 = x * w[1 * HD + t];
    float p2 = x * w[2 * HD + t];
#pragma unroll
    for (int off = 32; off > 0; off >>= 1) {
        p0 += __shfl_down(p0, off, 64);
        p1 += __shfl_down(p1, off, 64);
        p2 += __shfl_down(p2, off, 64);
    }
    __shared__ float red[2][3];
    if ((t & 63) == 0) { int wv = t >> 6; red[wv][0] = p0; red[wv][1] = p1; red[wv][2] = p2; }
    __syncthreads();
    if (t < 3) o[t] = red[0][t] + red[1][t] + bb[t];
}

// ---------------------------------------------------------------- launch
extern "C" void kernel_launch(void* const* d_in, const int* in_sizes, int n_in,
                              void* d_out, int out_size, void* d_ws, size_t ws_size,
                              hipStream_t stream)
{
    const float* x_p     = (const float*)d_in[0];
    const float* x_d     = (const float*)d_in[1];
    const int*   ei_pp   = (const int*)d_in[2];
    const int*   ei_dd   = (const int*)d_in[3];
    const int*   ei_p2d  = (const int*)d_in[4];
    const float* enc_p_w = (const float*)d_in[5];
    const float* enc_p_b = (const float*)d_in[6];
    const float* enc_d_w = (const float*)d_in[7];
    const float* enc_d_b = (const float*)d_in[8];
    const float* lin_l_w = (const float*)d_in[9];
    const float* lin_l_b = (const float*)d_in[10];
    const float* lin_r_w = (const float*)d_in[11];
    const float* dec_p_w = (const float*)d_in[12];
    const float* dec_p_b = (const float*)d_in[13];
    const float* dec_d_w = (const float*)d_in[14];
    const float* dec_d_b = (const float*)d_in[15];
    float* out = (float*)d_out;

    const int N = NN, E = EE;
    const size_t NHs = (size_t)N * HD;

    // ---- workspace layout: 4 feature buffers + CSR; total ~236 MB ----
    float* ws   = (float*)d_ws;
    float* A    = ws;
    float* B    = A + NHs;
    float* C    = B + NHs;
    float* D    = C + NHs;
    float* Wt   = D + NHs;                          // 4*384*128
    int*   deg     = (int*)(Wt + 4 * 384 * 128);    // 4*N
    int*   rowptr  = deg + 4 * (size_t)N;           // 4*(N+1)
    int*   cursor  = rowptr + 4 * (size_t)(N + 1);  // 4*N
    int*   esrc    = cursor + 4 * (size_t)N;        // 4*E

    const int* rp_pp  = rowptr;
    const int* rp_dd  = rowptr + (N + 1);
    const int* rp_p2d = rowptr + 2 * (N + 1);
    const int* rp_d2p = rowptr + 3 * (N + 1);
    const int* es_pp  = esrc;
    const int* es_dd  = esrc + E;
    const int* es_p2d = esrc + 2 * (size_t)E;
    const int* es_d2p = esrc + 3 * (size_t)E;

    #define BL(b_l, b_i) (lin_l_b + ((b_l) * 4 + (b_i)) * HD)

    // ---- CSR build (once per call; reused by both layers) ----
    hipMemsetAsync(deg, 0, 4 * (size_t)N * sizeof(int), stream);
    deg_kernel<<<(3 * E + 255) / 256, 256, 0, stream>>>(ei_pp, ei_dd, ei_p2d, deg, E, N);
    scan_kernel<<<4, 1024, 0, stream>>>(deg, rowptr, cursor, N);
    fill_kernel<<<(3 * E + 255) / 256, 256, 0, stream>>>(ei_pp, ei_dd, ei_p2d, cursor, esrc, E, N);
    prep_w_kernel<<<(4 * 384 * 128 + 255) / 256, 256, 0, stream>>>(lin_l_w, lin_r_w, Wt);

    // ---- encoders: hp -> A, hd -> B ----
    encoder_kernel<16><<<N, 128, 0, stream>>>(x_p, enc_p_w, enc_p_b, A, N);
    encoder_kernel<8><<<N, 128, 0, stream>>>(x_d, enc_d_w, enc_d_b, B, N);

    const int AGG_B = (N * 64 + 255) / 256;
    const int GEMM_B = (N + 31) / 32;

    // ---------------- layer 0 : hp=A, hd=B ----------------
    aggregate_kernel<<<AGG_B, 256, 0, stream>>>(A, rp_pp,  es_pp,  C, N);   // pp  -> C
    aggregate_kernel<<<AGG_B, 256, 0, stream>>>(B, rp_d2p, es_d2p, D, N);   // d2p -> D
    sage_gemm<<<GEMM_B, 256, 0, stream>>>(C, D, A, Wt + 0 * 384 * 128,
        BL(0, 0), BL(0, 3), D, N);                                          // new hp -> D
    aggregate_kernel<<<AGG_B, 256, 0, stream>>>(A, rp_p2d, es_p2d, C, N);   // p2d -> C (A dead after)
    aggregate_kernel<<<AGG_B, 256, 0, stream>>>(B, rp_dd,  es_dd,  A, N);   // dd  -> A
    sage_gemm<<<GEMM_B, 256, 0, stream>>>(A, C, B, Wt + 1 * 384 * 128,
        BL(0, 1), BL(0, 2), B, N);                                          // new hd -> B

    // ---------------- layer 1 : hp=D, hd=B ----------------
    aggregate_kernel<<<AGG_B, 256, 0, stream>>>(D, rp_pp,  es_pp,  A, N);   // pp  -> A
    aggregate_kernel<<<AGG_B, 256, 0, stream>>>(B, rp_d2p, es_d2p, C, N);   // d2p -> C
    sage_gemm<<<GEMM_B, 256, 0, stream>>>(A, C, D, Wt + 2 * 384 * 128,
        BL(1, 0), BL(1, 3), C, N);                                          // new hp -> C
    aggregate_kernel<<<AGG_B, 256, 0, stream>>>(D, rp_p2d, es_p2d, A, N);   // p2d -> A (D dead after)
    aggregate_kernel<<<AGG_B, 256, 0, stream>>>(B, rp_dd,  es_dd,  D, N);   // dd  -> D
    sage_gemm<<<GEMM_B, 256, 0, stream>>>(D, A, B, Wt + 3 * 384 * 128,
        BL(1, 1), BL(1, 2), B, N);                                          // new hd -> B

    // ---- decoders: primal from C, dual from B ----
    decoder_kernel<<<2 * N, 128, 0, stream>>>(C, B, dec_p_w, dec_p_b, dec_d_w, dec_d_b, out, N);

    #undef BL
}

// Round 5
// 2440.252 us; speedup vs baseline: 9.4319x; 1.4104x over previous
//
#include <hip/hip_runtime.h>
#include <hip/hip_bf16.h>

#define NN 100000
#define HD 128
#define EE 1600000
#define NTILES 98   // ceil(100000/1024)

typedef __hip_bfloat16 bf16;

__device__ inline float lo2f(unsigned u) { unsigned v = u << 16;        return __builtin_bit_cast(float, v); }
__device__ inline float hi2f(unsigned u) { unsigned v = u & 0xffff0000u; return __builtin_bit_cast(float, v); }
__device__ inline unsigned short f2bf_bits(float x) {
    bf16 b = __float2bfloat16(x);
    return *reinterpret_cast<unsigned short*>(&b);
}

// ---------------------------------------------------------------- degree count (int atomics)
// deg layout: [pp | dd | p2d | d2p], each N ints
__global__ __launch_bounds__(256) void deg_kernel(
    const int* __restrict__ ei_pp, const int* __restrict__ ei_dd,
    const int* __restrict__ ei_p2d, int* __restrict__ deg, int E, int N)
{
    int gid = blockIdx.x * 256 + threadIdx.x;
    if (gid < E) {
        atomicAdd(deg + ei_pp[E + gid], 1);
    } else if (gid < 2 * E) {
        int e = gid - E;
        atomicAdd(deg + N + ei_dd[E + e], 1);
    } else if (gid < 3 * E) {
        int e = gid - 2 * E;
        atomicAdd(deg + 2 * N + ei_p2d[E + e], 1);   // p2d: dst = dual (row1)
        atomicAdd(deg + 3 * N + ei_p2d[e], 1);       // d2p: dst = primal (row0)
    }
}

// ---------------------------------------------------------------- 3-phase parallel scan
// Phase A: per-1024-tile inclusive scan -> local exclusive to rowptr/cursor, tile totals to tsum
__global__ __launch_bounds__(1024) void scan_phaseA(
    const int* __restrict__ deg, int* __restrict__ rowptr,
    int* __restrict__ cursor, int* __restrict__ tsum, int n)
{
    int t = blockIdx.x / NTILES;
    int tile = blockIdx.x - t * NTILES;
    int i = tile * 1024 + threadIdx.x;
    int v = (i < n) ? deg[(size_t)t * n + i] : 0;
    __shared__ int s[1024];
    s[threadIdx.x] = v;
    __syncthreads();
    for (int off = 1; off < 1024; off <<= 1) {
        int x = (threadIdx.x >= off) ? s[threadIdx.x - off] : 0;
        __syncthreads();
        s[threadIdx.x] += x;
        __syncthreads();
    }
    int incl = s[threadIdx.x];
    if (i < n) {
        int ex = incl - v;
        rowptr[(size_t)t * (n + 1) + i] = ex;
        cursor[(size_t)t * n + i] = ex;
    }
    if (threadIdx.x == 1023) tsum[t * NTILES + tile] = incl;
}

// Phase B: 4 threads, each serially scans its CSR's 98 tile totals; writes rowptr[n]
__global__ void scan_phaseB(int* __restrict__ tsum, int* __restrict__ rowptr, int n)
{
    int t = threadIdx.x;
    if (t >= 4) return;
    int s = 0;
    for (int k = 0; k < NTILES; ++k) {
        int v = tsum[t * NTILES + k];
        tsum[t * NTILES + k] = s;
        s += v;
    }
    rowptr[(size_t)t * (n + 1) + n] = s;
}

// Phase C: add tile offsets
__global__ __launch_bounds__(1024) void scan_phaseC(
    int* __restrict__ rowptr, int* __restrict__ cursor,
    const int* __restrict__ tsum, int n)
{
    int t = blockIdx.x / NTILES;
    int tile = blockIdx.x - t * NTILES;
    int i = tile * 1024 + threadIdx.x;
    if (i < n) {
        int off = tsum[t * NTILES + tile];
        rowptr[(size_t)t * (n + 1) + i] += off;
        cursor[(size_t)t * n + i] += off;
    }
}

// ---------------------------------------------------------------- CSR bucket fill
// esrc layout: [pp | dd | p2d | d2p], each E ints
__global__ __launch_bounds__(256) void fill_kernel(
    const int* __restrict__ ei_pp, const int* __restrict__ ei_dd,
    const int* __restrict__ ei_p2d,
    int* __restrict__ cursor, int* __restrict__ esrc, int E, int N)
{
    int gid = blockIdx.x * 256 + threadIdx.x;
    if (gid < E) {
        int s = ei_pp[gid], dd = ei_pp[E + gid];
        int pos = atomicAdd(cursor + dd, 1);
        esrc[pos] = s;
    } else if (gid < 2 * E) {
        int e = gid - E;
        int s = ei_dd[e], dd = ei_dd[E + e];
        int pos = atomicAdd(cursor + N + dd, 1);
        esrc[E + pos] = s;
    } else if (gid < 3 * E) {
        int e = gid - 2 * E;
        int sp = ei_p2d[e], sd = ei_p2d[E + e];
        int pos = atomicAdd(cursor + 2 * N + sd, 1);   // p2d: dst dual, src primal
        esrc[2 * E + pos] = sp;
        pos = atomicAdd(cursor + 3 * N + sp, 1);       // d2p: dst primal, src dual
        esrc[3 * E + pos] = sd;
    }
}

// ---------------------------------------------------------------- gather aggregation (bf16 src, mean fused)
// one wave per destination node; 4 edges in flight (16-lane group each);
// lane handles 8 consecutive bf16 cols via one 16B load.
__global__ __launch_bounds__(256) void aggregate_kernel(
    const bf16* __restrict__ src, const int* __restrict__ rowptr,
    const int* __restrict__ esrc, float* __restrict__ out, int n)
{
    int node = (blockIdx.x * 256 + threadIdx.x) >> 6;
    if (node >= n) return;
    int lane = threadIdx.x & 63;
    int g  = lane >> 4;           // edge slot 0..3
    int c8 = (lane & 15) << 3;    // col base (8 cols)
    int beg = rowptr[node], end = rowptr[node + 1];
    float iv = 1.0f / fmaxf((float)(end - beg), 1.0f);
    float acc[8] = {};
    for (int e = beg + g; e < end; e += 4) {
        int s = esrc[e];
        const uint4 u = *reinterpret_cast<const uint4*>(src + (size_t)s * HD + c8);
        acc[0] += lo2f(u.x); acc[1] += hi2f(u.x);
        acc[2] += lo2f(u.y); acc[3] += hi2f(u.y);
        acc[4] += lo2f(u.z); acc[5] += hi2f(u.z);
        acc[6] += lo2f(u.w); acc[7] += hi2f(u.w);
    }
#pragma unroll
    for (int j = 0; j < 8; ++j) {
        acc[j] += __shfl_xor(acc[j], 16, 64);
        acc[j] += __shfl_xor(acc[j], 32, 64);
    }
    if (lane < 16) {
        float* dst = out + (size_t)node * HD + c8;
        float4 r0 = { acc[0] * iv, acc[1] * iv, acc[2] * iv, acc[3] * iv };
        float4 r1 = { acc[4] * iv, acc[5] * iv, acc[6] * iv, acc[7] * iv };
        *reinterpret_cast<float4*>(dst)     = r0;
        *reinterpret_cast<float4*>(dst + 4) = r1;
    }
}

// ------------------------------------------------- fused-weight prep
// Wt layout per cfg: [k=384][j=128], cfg: 0=l0 primal, 1=l0 dual, 2=l1 primal, 3=l1 dual
__global__ __launch_bounds__(256) void prep_w_kernel(
    const float* __restrict__ ll, const float* __restrict__ lr, float* __restrict__ Wt)
{
    int gid = blockIdx.x * 256 + threadIdx.x;
    if (gid >= 4 * 384 * 128) return;
    int cfg = gid / (384 * 128);
    int rem = gid - cfg * (384 * 128);
    int k = rem >> 7;
    int j = rem & 127;
    int l  = cfg >> 1;
    int ia = (cfg & 1) ? 1 : 0;   // agg1 weight index (pp / dd)
    int ib = (cfg & 1) ? 2 : 3;   // agg2 weight index (p2d / d2p)
    float v;
    if (k < 128)
        v = ll[((l * 4 + ia) * 128 + j) * 128 + k];
    else if (k < 256)
        v = ll[((l * 4 + ib) * 128 + j) * 128 + (k - 128)];
    else
        v = lr[((l * 4 + ia) * 128 + j) * 128 + (k - 256)]
          + lr[((l * 4 + ib) * 128 + j) * 128 + (k - 256)];
    Wt[gid] = v;
}

// ---------------------------------------------------------------- encoder (writes bf16)
template <int IN>
__global__ __launch_bounds__(128) void encoder_kernel(
    const float* __restrict__ x, const float* __restrict__ w,
    const float* __restrict__ b, bf16* __restrict__ h, int n)
{
    int node = blockIdx.x;
    int j = threadIdx.x;
    __shared__ float xs[IN];
    if (j < IN) xs[j] = x[node * IN + j];
    __syncthreads();
    float acc = b[j];
#pragma unroll
    for (int k = 0; k < IN; ++k) acc += xs[k] * w[j * IN + k];
    h[(size_t)node * HD + j] = __float2bfloat16(fmaxf(acc, 0.0f));
}

// ---------------------------------------------------------------- fused SAGE GEMM
// out[i][j] = relu(b1[j]+b2[j] + sum_k X[i][k]*Wt[k][j]), X = [agg1 | agg2 | h16], K=384.
// agg1/agg2 fp32 (pre-normalized); h16/out bf16. out MAY alias h16 (block-row disjoint,
// each block writes only its own rows after the K-loop).
__global__ __launch_bounds__(256) void sage_gemm(
    const float* __restrict__ agg1, const float* __restrict__ agg2,
    const bf16* h16, const float* __restrict__ Wt,
    const float* __restrict__ b1, const float* __restrict__ b2,
    bf16* out, int n)
{
    __shared__ __align__(16) float Ws[32][128];
    __shared__ __align__(16) float Xs[32][36];
    const int tid = threadIdx.x;
    const int tj = tid & 31;   // col group: cols tj*4..tj*4+3
    const int ti = tid >> 5;   // node group: nodes ti*4..ti*4+3
    const int nodeBase = blockIdx.x * 32;
    float acc[4][4] = {};

    for (int k0 = 0; k0 < 384; k0 += 32) {
        const int ksub = k0 & 127;
#pragma unroll
        for (int it = 0; it < 16; ++it) {
            int idx = it * 256 + tid;
            Ws[idx >> 7][idx & 127] = Wt[(k0 + (idx >> 7)) * 128 + (idx & 127)];
        }
#pragma unroll
        for (int it = 0; it < 4; ++it) {
            int idx = it * 256 + tid;
            int i = idx >> 5, kk = idx & 31;
            int node = nodeBase + i;
            float v = 0.0f;
            if (node < n) {
                if (k0 < 128)       v = agg1[(size_t)node * HD + ksub + kk];
                else if (k0 < 256)  v = agg2[(size_t)node * HD + ksub + kk];
                else                v = __bfloat162float(h16[(size_t)node * HD + ksub + kk]);
            }
            Xs[kk][i] = v;
        }
        __syncthreads();
#pragma unroll
        for (int kk = 0; kk < 32; ++kk) {
            const float4 xv = *reinterpret_cast<const float4*>(&Xs[kk][ti * 4]);
            const float4 wv = *reinterpret_cast<const float4*>(&Ws[kk][tj * 4]);
            acc[0][0] += xv.x * wv.x; acc[0][1] += xv.x * wv.y; acc[0][2] += xv.x * wv.z; acc[0][3] += xv.x * wv.w;
            acc[1][0] += xv.y * wv.x; acc[1][1] += xv.y * wv.y; acc[1][2] += xv.y * wv.z; acc[1][3] += xv.y * wv.w;
            acc[2][0] += xv.z * wv.x; acc[2][1] += xv.z * wv.y; acc[2][2] += xv.z * wv.z; acc[2][3] += xv.z * wv.w;
            acc[3][0] += xv.w * wv.x; acc[3][1] += xv.w * wv.y; acc[3][2] += xv.w * wv.z; acc[3][3] += xv.w * wv.w;
        }
        __syncthreads();
    }

    float4 bias;
    bias.x = b1[tj * 4 + 0] + b2[tj * 4 + 0];
    bias.y = b1[tj * 4 + 1] + b2[tj * 4 + 1];
    bias.z = b1[tj * 4 + 2] + b2[tj * 4 + 2];
    bias.w = b1[tj * 4 + 3] + b2[tj * 4 + 3];
#pragma unroll
    for (int a = 0; a < 4; ++a) {
        int node = nodeBase + ti * 4 + a;
        if (node < n) {
            ushort4 st;
            st.x = f2bf_bits(fmaxf(acc[a][0] + bias.x, 0.0f));
            st.y = f2bf_bits(fmaxf(acc[a][1] + bias.y, 0.0f));
            st.z = f2bf_bits(fmaxf(acc[a][2] + bias.z, 0.0f));
            st.w = f2bf_bits(fmaxf(acc[a][3] + bias.w, 0.0f));
            *reinterpret_cast<ushort4*>(out + (size_t)node * HD + tj * 4) = st;
        }
    }
}

// ---------------------------------------------------------------- decoder (OUT=3, bf16 h)
__global__ __launch_bounds__(128) void decoder_kernel(
    const bf16* __restrict__ hp, const bf16* __restrict__ hd,
    const float* __restrict__ wp, const float* __restrict__ bp,
    const float* __restrict__ wd, const float* __restrict__ bd,
    float* __restrict__ out, int n)
{
    int b = blockIdx.x;
    const bf16* h; const float* w; const float* bb; float* o;
    if (b < n) { h = hp + (size_t)b * HD; w = wp; bb = bp; o = out + (size_t)b * 3; }
    else { int nd = b - n; h = hd + (size_t)nd * HD; w = wd; bb = bd; o = out + (size_t)n * 3 + (size_t)nd * 3; }
    int t = threadIdx.x;
    float x = __bfloat162float(h[t]);
    float p0 = x * w[0 * HD + t];
    float p1 = x * w[1 * HD + t];
    float p2 = x * w[2 * HD + t];
#pragma unroll
    for (int off = 32; off > 0; off >>= 1) {
        p0 += __shfl_down(p0, off, 64);
        p1 += __shfl_down(p1, off, 64);
        p2 += __shfl_down(p2, off, 64);
    }
    __shared__ float red[2][3];
    if ((t & 63) == 0) { int wv = t >> 6; red[wv][0] = p0; red[wv][1] = p1; red[wv][2] = p2; }
    __syncthreads();
    if (t < 3) o[t] = red[0][t] + red[1][t] + bb[t];
}

// ---------------------------------------------------------------- launch
extern "C" void kernel_launch(void* const* d_in, const int* in_sizes, int n_in,
                              void* d_out, int out_size, void* d_ws, size_t ws_size,
                              hipStream_t stream)
{
    const float* x_p     = (const float*)d_in[0];
    const float* x_d     = (const float*)d_in[1];
    const int*   ei_pp   = (const int*)d_in[2];
    const int*   ei_dd   = (const int*)d_in[3];
    const int*   ei_p2d  = (const int*)d_in[4];
    const float* enc_p_w = (const float*)d_in[5];
    const float* enc_p_b = (const float*)d_in[6];
    const float* enc_d_w = (const float*)d_in[7];
    const float* enc_d_b = (const float*)d_in[8];
    const float* lin_l_w = (const float*)d_in[9];
    const float* lin_l_b = (const float*)d_in[10];
    const float* lin_r_w = (const float*)d_in[11];
    const float* dec_p_w = (const float*)d_in[12];
    const float* dec_p_b = (const float*)d_in[13];
    const float* dec_d_w = (const float*)d_in[14];
    const float* dec_d_b = (const float*)d_in[15];
    float* out = (float*)d_out;

    const int N = NN, E = EE;
    const size_t NHs = (size_t)N * HD;

    // ---- workspace layout (~210 MB): 2 fp32 agg + Wt + 3 bf16 h + CSR ----
    float* ws  = (float*)d_ws;
    float* G1  = ws;                       // N*HD fp32
    float* G2  = G1 + NHs;                 // N*HD fp32
    float* Wt  = G2 + NHs;                 // 4*384*128 fp32
    bf16*  Hp  = (bf16*)(Wt + 4 * 384 * 128);  // N*HD bf16
    bf16*  Hd  = Hp + NHs;
    bf16*  Ht  = Hd + NHs;
    int*   deg     = (int*)(Ht + NHs);             // 4*N
    int*   rowptr  = deg + 4 * (size_t)N;          // 4*(N+1)
    int*   cursor  = rowptr + 4 * (size_t)(N + 1); // 4*N
    int*   esrc    = cursor + 4 * (size_t)N;       // 4*E
    int*   tsum    = esrc + 4 * (size_t)E;         // 4*NTILES

    const int* rp_pp  = rowptr;
    const int* rp_dd  = rowptr + (N + 1);
    const int* rp_p2d = rowptr + 2 * (N + 1);
    const int* rp_d2p = rowptr + 3 * (N + 1);
    const int* es_pp  = esrc;
    const int* es_dd  = esrc + E;
    const int* es_p2d = esrc + 2 * (size_t)E;
    const int* es_d2p = esrc + 3 * (size_t)E;

    #define BL(b_l, b_i) (lin_l_b + ((b_l) * 4 + (b_i)) * HD)

    // ---- CSR build (once per call; reused by both layers) ----
    hipMemsetAsync(deg, 0, 4 * (size_t)N * sizeof(int), stream);
    deg_kernel<<<(3 * E + 255) / 256, 256, 0, stream>>>(ei_pp, ei_dd, ei_p2d, deg, E, N);
    scan_phaseA<<<4 * NTILES, 1024, 0, stream>>>(deg, rowptr, cursor, tsum, N);
    scan_phaseB<<<1, 4, 0, stream>>>(tsum, rowptr, N);
    scan_phaseC<<<4 * NTILES, 1024, 0, stream>>>(rowptr, cursor, tsum, N);
    fill_kernel<<<(3 * E + 255) / 256, 256, 0, stream>>>(ei_pp, ei_dd, ei_p2d, cursor, esrc, E, N);
    prep_w_kernel<<<(4 * 384 * 128 + 255) / 256, 256, 0, stream>>>(lin_l_w, lin_r_w, Wt);

    // ---- encoders: hp -> Hp, hd -> Hd ----
    encoder_kernel<16><<<N, 128, 0, stream>>>(x_p, enc_p_w, enc_p_b, Hp, N);
    encoder_kernel<8><<<N, 128, 0, stream>>>(x_d, enc_d_w, enc_d_b, Hd, N);

    const int AGG_B = (N * 64 + 255) / 256;
    const int GEMM_B = (N + 31) / 32;

    // ---------------- layer 0 : hp=Hp, hd=Hd ----------------
    aggregate_kernel<<<AGG_B, 256, 0, stream>>>(Hp, rp_pp,  es_pp,  G1, N);   // pp  -> G1
    aggregate_kernel<<<AGG_B, 256, 0, stream>>>(Hd, rp_d2p, es_d2p, G2, N);   // d2p -> G2
    sage_gemm<<<GEMM_B, 256, 0, stream>>>(G1, G2, Hp, Wt + 0 * 384 * 128,
        BL(0, 0), BL(0, 3), Ht, N);                                           // new hp -> Ht
    aggregate_kernel<<<AGG_B, 256, 0, stream>>>(Hd, rp_dd,  es_dd,  G1, N);   // dd  -> G1
    aggregate_kernel<<<AGG_B, 256, 0, stream>>>(Hp, rp_p2d, es_p2d, G2, N);   // p2d -> G2 (old Hp)
    sage_gemm<<<GEMM_B, 256, 0, stream>>>(G1, G2, Hd, Wt + 1 * 384 * 128,
        BL(0, 1), BL(0, 2), Hd, N);                                           // new hd -> Hd (in-place)

    // ---------------- layer 1 : hp=Ht, hd=Hd ----------------
    aggregate_kernel<<<AGG_B, 256, 0, stream>>>(Ht, rp_pp,  es_pp,  G1, N);   // pp  -> G1
    aggregate_kernel<<<AGG_B, 256, 0, stream>>>(Hd, rp_d2p, es_d2p, G2, N);   // d2p -> G2
    sage_gemm<<<GEMM_B, 256, 0, stream>>>(G1, G2, Ht, Wt + 2 * 384 * 128,
        BL(1, 0), BL(1, 3), Hp, N);                                           // new hp -> Hp (free)
    aggregate_kernel<<<AGG_B, 256, 0, stream>>>(Hd, rp_dd,  es_dd,  G1, N);   // dd  -> G1
    aggregate_kernel<<<AGG_B, 256, 0, stream>>>(Ht, rp_p2d, es_p2d, G2, N);   // p2d -> G2 (old Ht)
    sage_gemm<<<GEMM_B, 256, 0, stream>>>(G1, G2, Hd, Wt + 3 * 384 * 128,
        BL(1, 1), BL(1, 2), Hd, N);                                           // new hd -> Hd (in-place)

    // ---- decoders: primal from Hp, dual from Hd ----
    decoder_kernel<<<2 * N, 128, 0, stream>>>(Hp, Hd, dec_p_w, dec_p_b, dec_d_w, dec_d_b, out, N);

    #undef BL
}

// Round 6
// 2035.519 us; speedup vs baseline: 11.3073x; 1.1988x over previous
//
#include <hip/hip_runtime.h>
#include <hip/hip_bf16.h>

#define NN 100000
#define HD 128
#define EE 1600000
#define NTILES 98   // ceil(100000/1024)

typedef __hip_bfloat16 bf16;
typedef short short8 __attribute__((ext_vector_type(8)));
typedef float f32x4 __attribute__((ext_vector_type(4)));

__device__ inline float lo2f(unsigned u) { unsigned v = u << 16;        return __builtin_bit_cast(float, v); }
__device__ inline float hi2f(unsigned u) { unsigned v = u & 0xffff0000u; return __builtin_bit_cast(float, v); }
__device__ inline unsigned short f2bf_bits(float x) {
    bf16 b = __float2bfloat16(x);
    return *reinterpret_cast<unsigned short*>(&b);
}

// ---------------------------------------------------------------- degree count (int atomics)
// deg layout: [pp | dd | p2d | d2p], each N ints
__global__ __launch_bounds__(256) void deg_kernel(
    const int* __restrict__ ei_pp, const int* __restrict__ ei_dd,
    const int* __restrict__ ei_p2d, int* __restrict__ deg, int E, int N)
{
    int gid = blockIdx.x * 256 + threadIdx.x;
    if (gid < E) {
        atomicAdd(deg + ei_pp[E + gid], 1);
    } else if (gid < 2 * E) {
        int e = gid - E;
        atomicAdd(deg + N + ei_dd[E + e], 1);
    } else if (gid < 3 * E) {
        int e = gid - 2 * E;
        atomicAdd(deg + 2 * N + ei_p2d[E + e], 1);   // p2d: dst = dual (row1)
        atomicAdd(deg + 3 * N + ei_p2d[e], 1);       // d2p: dst = primal (row0)
    }
}

// ---------------------------------------------------------------- 3-phase parallel scan
__global__ __launch_bounds__(1024) void scan_phaseA(
    const int* __restrict__ deg, int* __restrict__ rowptr,
    int* __restrict__ cursor, int* __restrict__ tsum, int n)
{
    int t = blockIdx.x / NTILES;
    int tile = blockIdx.x - t * NTILES;
    int i = tile * 1024 + threadIdx.x;
    int v = (i < n) ? deg[(size_t)t * n + i] : 0;
    __shared__ int s[1024];
    s[threadIdx.x] = v;
    __syncthreads();
    for (int off = 1; off < 1024; off <<= 1) {
        int x = (threadIdx.x >= off) ? s[threadIdx.x - off] : 0;
        __syncthreads();
        s[threadIdx.x] += x;
        __syncthreads();
    }
    int incl = s[threadIdx.x];
    if (i < n) {
        int ex = incl - v;
        rowptr[(size_t)t * (n + 1) + i] = ex;
        cursor[(size_t)t * n + i] = ex;
    }
    if (threadIdx.x == 1023) tsum[t * NTILES + tile] = incl;
}

__global__ void scan_phaseB(int* __restrict__ tsum, int* __restrict__ rowptr, int n)
{
    int t = threadIdx.x;
    if (t >= 4) return;
    int s = 0;
    for (int k = 0; k < NTILES; ++k) {
        int v = tsum[t * NTILES + k];
        tsum[t * NTILES + k] = s;
        s += v;
    }
    rowptr[(size_t)t * (n + 1) + n] = s;
}

__global__ __launch_bounds__(1024) void scan_phaseC(
    int* __restrict__ rowptr, int* __restrict__ cursor,
    const int* __restrict__ tsum, int n)
{
    int t = blockIdx.x / NTILES;
    int tile = blockIdx.x - t * NTILES;
    int i = tile * 1024 + threadIdx.x;
    if (i < n) {
        int off = tsum[t * NTILES + tile];
        rowptr[(size_t)t * (n + 1) + i] += off;
        cursor[(size_t)t * n + i] += off;
    }
}

// ---------------------------------------------------------------- CSR bucket fill
__global__ __launch_bounds__(256) void fill_kernel(
    const int* __restrict__ ei_pp, const int* __restrict__ ei_dd,
    const int* __restrict__ ei_p2d,
    int* __restrict__ cursor, int* __restrict__ esrc, int E, int N)
{
    int gid = blockIdx.x * 256 + threadIdx.x;
    if (gid < E) {
        int s = ei_pp[gid], dd = ei_pp[E + gid];
        int pos = atomicAdd(cursor + dd, 1);
        esrc[pos] = s;
    } else if (gid < 2 * E) {
        int e = gid - E;
        int s = ei_dd[e], dd = ei_dd[E + e];
        int pos = atomicAdd(cursor + N + dd, 1);
        esrc[E + pos] = s;
    } else if (gid < 3 * E) {
        int e = gid - 2 * E;
        int sp = ei_p2d[e], sd = ei_p2d[E + e];
        int pos = atomicAdd(cursor + 2 * N + sd, 1);   // p2d: dst dual, src primal
        esrc[2 * E + pos] = sp;
        pos = atomicAdd(cursor + 3 * N + sp, 1);       // d2p: dst primal, src dual
        esrc[3 * E + pos] = sd;
    }
}

// ---------------------------------------------------------------- gather aggregation (bf16 in/out, mean fused)
// one wave per destination node; 4 edges in flight (16-lane group each);
// lane handles 8 consecutive bf16 cols via one 16B load.
__global__ __launch_bounds__(256) void aggregate_kernel(
    const bf16* __restrict__ src, const int* __restrict__ rowptr,
    const int* __restrict__ esrc, bf16* __restrict__ out, int n)
{
    int node = (blockIdx.x * 256 + threadIdx.x) >> 6;
    if (node >= n) return;
    int lane = threadIdx.x & 63;
    int g  = lane >> 4;           // edge slot 0..3
    int c8 = (lane & 15) << 3;    // col base (8 cols)
    int beg = rowptr[node], end = rowptr[node + 1];
    float iv = 1.0f / fmaxf((float)(end - beg), 1.0f);
    float acc[8] = {};
    for (int e = beg + g; e < end; e += 4) {
        int s = esrc[e];
        const uint4 u = *reinterpret_cast<const uint4*>(src + (size_t)s * HD + c8);
        acc[0] += lo2f(u.x); acc[1] += hi2f(u.x);
        acc[2] += lo2f(u.y); acc[3] += hi2f(u.y);
        acc[4] += lo2f(u.z); acc[5] += hi2f(u.z);
        acc[6] += lo2f(u.w); acc[7] += hi2f(u.w);
    }
#pragma unroll
    for (int j = 0; j < 8; ++j) {
        acc[j] += __shfl_xor(acc[j], 16, 64);
        acc[j] += __shfl_xor(acc[j], 32, 64);
    }
    if (lane < 16) {
        uint4 u;
        u.x = (unsigned)f2bf_bits(acc[0] * iv) | ((unsigned)f2bf_bits(acc[1] * iv) << 16);
        u.y = (unsigned)f2bf_bits(acc[2] * iv) | ((unsigned)f2bf_bits(acc[3] * iv) << 16);
        u.z = (unsigned)f2bf_bits(acc[4] * iv) | ((unsigned)f2bf_bits(acc[5] * iv) << 16);
        u.w = (unsigned)f2bf_bits(acc[6] * iv) | ((unsigned)f2bf_bits(acc[7] * iv) << 16);
        *reinterpret_cast<uint4*>(out + (size_t)node * HD + c8) = u;
    }
}

// ------------------------------------------------- fused-weight prep (transposed, hi+lo bf16 split)
// WtT layout per cfg: [j=128 cols][k=384], cfg: 0=l0 primal, 1=l0 dual, 2=l1 primal, 3=l1 dual
__global__ __launch_bounds__(256) void prep_w_kernel(
    const float* __restrict__ ll, const float* __restrict__ lr,
    unsigned short* __restrict__ whi, unsigned short* __restrict__ wlo)
{
    int gid = blockIdx.x * 256 + threadIdx.x;
    if (gid >= 4 * 384 * 128) return;
    int cfg = gid / (384 * 128);
    int rem = gid - cfg * (384 * 128);
    int k = rem >> 7;
    int j = rem & 127;
    int l  = cfg >> 1;
    int ia = (cfg & 1) ? 1 : 0;   // agg1 weight index (pp / dd)
    int ib = (cfg & 1) ? 2 : 3;   // agg2 weight index (p2d / d2p)
    float v;
    if (k < 128)
        v = ll[((l * 4 + ia) * 128 + j) * 128 + k];
    else if (k < 256)
        v = ll[((l * 4 + ib) * 128 + j) * 128 + (k - 128)];
    else
        v = lr[((l * 4 + ia) * 128 + j) * 128 + (k - 256)]
          + lr[((l * 4 + ib) * 128 + j) * 128 + (k - 256)];
    unsigned short hb = f2bf_bits(v);
    float hf = hi2f((unsigned)hb << 16);
    unsigned short lb = f2bf_bits(v - hf);
    size_t o = (size_t)cfg * (128 * 384) + (size_t)j * 384 + k;
    whi[o] = hb;
    wlo[o] = lb;
}

// ---------------------------------------------------------------- encoder (writes bf16)
template <int IN>
__global__ __launch_bounds__(128) void encoder_kernel(
    const float* __restrict__ x, const float* __restrict__ w,
    const float* __restrict__ b, bf16* __restrict__ h, int n)
{
    int node = blockIdx.x;
    int j = threadIdx.x;
    __shared__ float xs[IN];
    if (j < IN) xs[j] = x[node * IN + j];
    __syncthreads();
    float acc = b[j];
#pragma unroll
    for (int k = 0; k < IN; ++k) acc += xs[k] * w[j * IN + k];
    h[(size_t)node * HD + j] = __float2bfloat16(fmaxf(acc, 0.0f));
}

// ---------------------------------------------------------------- MFMA SAGE GEMM
// out[r][c] = relu(b1[c]+b2[c] + sum_k X[r][k]*W[k][c]), X = [g1 | g2 | h] bf16, K=384.
// W split hi+lo bf16 (WtT[c][k]); fp32 MFMA accumulation. Per wave: 32 rows x 128 cols
// (2 M-tiles x 8 N-tiles of 16x16), K-steps of 32 via mfma_f32_16x16x32_bf16.
// Fragment layout: A row=lane&15, k=(lane>>4)*8+j ; B col=lane&15, same k ;
// D col=lane&15, row=(lane>>4)*4+reg (m89-verified).
// out MAY alias any input h-buffer: each wave reads only its own 32 rows and
// writes them only after the K-loop.
__global__ __launch_bounds__(256) void mfma_gemm(
    const bf16* __restrict__ g1, const bf16* __restrict__ g2,
    const bf16* hsrc,
    const unsigned short* __restrict__ whi, const unsigned short* __restrict__ wlo,
    const float* __restrict__ b1, const float* __restrict__ b2,
    bf16* out, int n)
{
    const int tid = threadIdx.x;
    const int wave = blockIdx.x * 4 + (tid >> 6);
    const int rowBase = wave * 32;
    if (rowBase >= n) return;
    const int lane = tid & 63;
    const int lr = lane & 15;
    const int kg = lane >> 4;

    f32x4 acc[2][8];
#pragma unroll
    for (int m = 0; m < 2; ++m)
#pragma unroll
        for (int t = 0; t < 8; ++t) acc[m][t] = (f32x4){0.f, 0.f, 0.f, 0.f};

#pragma unroll
    for (int t = 0; t < 12; ++t) {
        const bf16* xs = (t < 4) ? g1 : ((t < 8) ? g2 : hsrc);
        const int kin = ((t & 3) << 5) + (kg << 3);
        short8 a0 = *reinterpret_cast<const short8*>(xs + (size_t)(rowBase + lr) * HD + kin);
        short8 a1 = *reinterpret_cast<const short8*>(xs + (size_t)(rowBase + 16 + lr) * HD + kin);
        const int kofs = (t << 5) + (kg << 3);
#pragma unroll
        for (int nt = 0; nt < 8; ++nt) {
            short8 bh = *reinterpret_cast<const short8*>(whi + (size_t)(nt * 16 + lr) * 384 + kofs);
            short8 bl = *reinterpret_cast<const short8*>(wlo + (size_t)(nt * 16 + lr) * 384 + kofs);
            acc[0][nt] = __builtin_amdgcn_mfma_f32_16x16x32_bf16(a0, bh, acc[0][nt], 0, 0, 0);
            acc[1][nt] = __builtin_amdgcn_mfma_f32_16x16x32_bf16(a1, bh, acc[1][nt], 0, 0, 0);
            acc[0][nt] = __builtin_amdgcn_mfma_f32_16x16x32_bf16(a0, bl, acc[0][nt], 0, 0, 0);
            acc[1][nt] = __builtin_amdgcn_mfma_f32_16x16x32_bf16(a1, bl, acc[1][nt], 0, 0, 0);
        }
    }

#pragma unroll
    for (int nt = 0; nt < 8; ++nt) {
        int c = nt * 16 + lr;
        float bias = b1[c] + b2[c];
#pragma unroll
        for (int m = 0; m < 2; ++m) {
#pragma unroll
            for (int r = 0; r < 4; ++r) {
                int row = rowBase + m * 16 + kg * 4 + r;
                float v = fmaxf(acc[m][nt][r] + bias, 0.0f);
                out[(size_t)row * HD + c] = __float2bfloat16(v);
            }
        }
    }
}

// ---------------------------------------------------------------- decoder (OUT=3, bf16 h)
__global__ __launch_bounds__(128) void decoder_kernel(
    const bf16* __restrict__ hp, const bf16* __restrict__ hd,
    const float* __restrict__ wp, const float* __restrict__ bp,
    const float* __restrict__ wd, const float* __restrict__ bd,
    float* __restrict__ out, int n)
{
    int b = blockIdx.x;
    const bf16* h; const float* w; const float* bb; float* o;
    if (b < n) { h = hp + (size_t)b * HD; w = wp; bb = bp; o = out + (size_t)b * 3; }
    else { int nd = b - n; h = hd + (size_t)nd * HD; w = wd; bb = bd; o = out + (size_t)n * 3 + (size_t)nd * 3; }
    int t = threadIdx.x;
    float x = __bfloat162float(h[t]);
    float p0 = x * w[0 * HD + t];
    float p1 = x * w[1 * HD + t];
    float p2 = x * w[2 * HD + t];
#pragma unroll
    for (int off = 32; off > 0; off >>= 1) {
        p0 += __shfl_down(p0, off, 64);
        p1 += __shfl_down(p1, off, 64);
        p2 += __shfl_down(p2, off, 64);
    }
    __shared__ float red[2][3];
    if ((t & 63) == 0) { int wv = t >> 6; red[wv][0] = p0; red[wv][1] = p1; red[wv][2] = p2; }
    __syncthreads();
    if (t < 3) o[t] = red[0][t] + red[1][t] + bb[t];
}

// ---------------------------------------------------------------- launch
extern "C" void kernel_launch(void* const* d_in, const int* in_sizes, int n_in,
                              void* d_out, int out_size, void* d_ws, size_t ws_size,
                              hipStream_t stream)
{
    const float* x_p     = (const float*)d_in[0];
    const float* x_d     = (const float*)d_in[1];
    const int*   ei_pp   = (const int*)d_in[2];
    const int*   ei_dd   = (const int*)d_in[3];
    const int*   ei_p2d  = (const int*)d_in[4];
    const float* enc_p_w = (const float*)d_in[5];
    const float* enc_p_b = (const float*)d_in[6];
    const float* enc_d_w = (const float*)d_in[7];
    const float* enc_d_b = (const float*)d_in[8];
    const float* lin_l_w = (const float*)d_in[9];
    const float* lin_l_b = (const float*)d_in[10];
    const float* lin_r_w = (const float*)d_in[11];
    const float* dec_p_w = (const float*)d_in[12];
    const float* dec_p_b = (const float*)d_in[13];
    const float* dec_d_w = (const float*)d_in[14];
    const float* dec_d_b = (const float*)d_in[15];
    float* out = (float*)d_out;

    const int N = NN, E = EE;
    const size_t NHs = (size_t)N * HD;

    // ---- workspace layout (~160 MB): 5 bf16 feature buffers + WtT hi/lo + CSR ----
    bf16* G1 = (bf16*)d_ws;
    bf16* G2 = G1 + NHs;
    bf16* Hp = G2 + NHs;
    bf16* Hd = Hp + NHs;
    bf16* Ht = Hd + NHs;
    unsigned short* Whi = (unsigned short*)(Ht + NHs);   // 4*128*384
    unsigned short* Wlo = Whi + 4 * 128 * 384;
    int*   deg     = (int*)(Wlo + 4 * 128 * 384);   // 4*N
    int*   rowptr  = deg + 4 * (size_t)N;           // 4*(N+1)
    int*   cursor  = rowptr + 4 * (size_t)(N + 1);  // 4*N
    int*   esrc    = cursor + 4 * (size_t)N;        // 4*E
    int*   tsum    = esrc + 4 * (size_t)E;          // 4*NTILES

    const int* rp_pp  = rowptr;
    const int* rp_dd  = rowptr + (N + 1);
    const int* rp_p2d = rowptr + 2 * (N + 1);
    const int* rp_d2p = rowptr + 3 * (N + 1);
    const int* es_pp  = esrc;
    const int* es_dd  = esrc + E;
    const int* es_p2d = esrc + 2 * (size_t)E;
    const int* es_d2p = esrc + 3 * (size_t)E;

    #define BL(b_l, b_i) (lin_l_b + ((b_l) * 4 + (b_i)) * HD)
    #define WT(cfg) (Whi + (size_t)(cfg) * 128 * 384), (Wlo + (size_t)(cfg) * 128 * 384)

    // ---- CSR build (once per call; reused by both layers) ----
    hipMemsetAsync(deg, 0, 4 * (size_t)N * sizeof(int), stream);
    deg_kernel<<<(3 * E + 255) / 256, 256, 0, stream>>>(ei_pp, ei_dd, ei_p2d, deg, E, N);
    scan_phaseA<<<4 * NTILES, 1024, 0, stream>>>(deg, rowptr, cursor, tsum, N);
    scan_phaseB<<<1, 4, 0, stream>>>(tsum, rowptr, N);
    scan_phaseC<<<4 * NTILES, 1024, 0, stream>>>(rowptr, cursor, tsum, N);
    fill_kernel<<<(3 * E + 255) / 256, 256, 0, stream>>>(ei_pp, ei_dd, ei_p2d, cursor, esrc, E, N);
    prep_w_kernel<<<(4 * 384 * 128 + 255) / 256, 256, 0, stream>>>(lin_l_w, lin_r_w, Whi, Wlo);

    // ---- encoders: hp -> Hp, hd -> Hd ----
    encoder_kernel<16><<<N, 128, 0, stream>>>(x_p, enc_p_w, enc_p_b, Hp, N);
    encoder_kernel<8><<<N, 128, 0, stream>>>(x_d, enc_d_w, enc_d_b, Hd, N);

    const int AGG_B  = (N * 64 + 255) / 256;
    const int GEMM_B = ((N + 31) / 32 + 3) / 4;   // waves of 32 rows, 4 waves/block

    // ---------------- layer 0 : hp=Hp, hd=Hd ----------------
    aggregate_kernel<<<AGG_B, 256, 0, stream>>>(Hp, rp_pp,  es_pp,  G1, N);   // pp  -> G1
    aggregate_kernel<<<AGG_B, 256, 0, stream>>>(Hd, rp_d2p, es_d2p, G2, N);   // d2p -> G2
    mfma_gemm<<<GEMM_B, 256, 0, stream>>>(G1, G2, Hp, WT(0),
        BL(0, 0), BL(0, 3), Ht, N);                                           // new hp -> Ht
    aggregate_kernel<<<AGG_B, 256, 0, stream>>>(Hd, rp_dd,  es_dd,  G1, N);   // dd  -> G1
    aggregate_kernel<<<AGG_B, 256, 0, stream>>>(Hp, rp_p2d, es_p2d, G2, N);   // p2d -> G2
    mfma_gemm<<<GEMM_B, 256, 0, stream>>>(G1, G2, Hd, WT(1),
        BL(0, 1), BL(0, 2), Hd, N);                                           // new hd -> Hd (in-place)

    // ---------------- layer 1 : hp=Ht, hd=Hd ----------------
    aggregate_kernel<<<AGG_B, 256, 0, stream>>>(Ht, rp_pp,  es_pp,  G1, N);   // pp  -> G1
    aggregate_kernel<<<AGG_B, 256, 0, stream>>>(Hd, rp_d2p, es_d2p, G2, N);   // d2p -> G2
    mfma_gemm<<<GEMM_B, 256, 0, stream>>>(G1, G2, Ht, WT(2),
        BL(1, 0), BL(1, 3), Hp, N);                                           // new hp -> Hp
    aggregate_kernel<<<AGG_B, 256, 0, stream>>>(Hd, rp_dd,  es_dd,  G1, N);   // dd  -> G1
    aggregate_kernel<<<AGG_B, 256, 0, stream>>>(Ht, rp_p2d, es_p2d, G2, N);   // p2d -> G2
    mfma_gemm<<<GEMM_B, 256, 0, stream>>>(G1, G2, Hd, WT(3),
        BL(1, 1), BL(1, 2), Hd, N);                                           // new hd -> Hd (in-place)

    // ---- decoders: primal from Hp, dual from Hd ----
    decoder_kernel<<<2 * N, 128, 0, stream>>>(Hp, Hd, dec_p_w, dec_p_b, dec_d_w, dec_d_b, out, N);

    #undef WT
    #undef BL
}